// Round 1
// baseline (5454.860 us; speedup 1.0000x reference)
//
#include <hip/hip_runtime.h>
#include <math.h>

#define NIT 200
#define NN 128
#define TI 4
#define TJ 8
#define GI 32   // NN/TI
#define GJ 16   // NN/TJ
#define NTHREADS 512
#define NWAVES 8

__global__ __launch_bounds__(NTHREADS, 1)
void tv_kernel(const float* __restrict__ Min, const float* __restrict__ tvr,
               float* __restrict__ out, int Nb)
{
  const float MUc = 0.25f;
  const int b   = blockIdx.x;
  const int tid = threadIdx.x;
  const int tx  = tid & (GJ - 1);   // 0..15
  const int ty  = tid >> 4;         // 0..31
  const int lane = tid & 63;
  const int wv   = tid >> 6;
  const int i0 = ty * TI;
  const int j0 = tx * TJ;

  __shared__ float  sTop[GI][GJ][TJ];   // 16 KB  row-halo exchange
  __shared__ float  sLeft[GI][GJ][TI];  //  8 KB  col-halo exchange
  __shared__ float4 sRed[2][NWAVES];    // 256 B  parity-buffered reduction

  const float r = tvr[0];

  // register-resident fields: M, u (2 comps), xi (2 comps), scratch t
  float m[TI][TJ], ux[TI][TJ], uy[TI][TJ], xx[TI][TJ], xy[TI][TJ], t[TI][TJ];

  const float* Mb = Min + (size_t)b * NN * NN;
#pragma unroll
  for (int di = 0; di < TI; ++di)
#pragma unroll
    for (int dj = 0; dj < TJ; ++dj) {
      m[di][dj] = Mb[(i0 + di) * NN + (j0 + dj)];
      ux[di][dj] = 0.f; uy[di][dj] = 0.f;
      xx[di][dj] = 0.f; xy[di][dj] = 0.f;
      t[di][dj] = 0.f;
    }

  int par = 0;
  // block-wide sum of 4 floats; returns identical value on every thread.
  auto blk_red4 = [&](float v0, float v1, float v2, float v3) {
#pragma unroll
    for (int off = 32; off >= 1; off >>= 1) {
      v0 += __shfl_xor(v0, off, 64);
      v1 += __shfl_xor(v1, off, 64);
      v2 += __shfl_xor(v2, off, 64);
      v3 += __shfl_xor(v3, off, 64);
    }
    if (lane == 0) sRed[par][wv] = make_float4(v0, v1, v2, v3);
    __syncthreads();
    float4 acc = make_float4(0.f, 0.f, 0.f, 0.f);
#pragma unroll
    for (int w = 0; w < NWAVES; ++w) {
      float4 q = sRed[par][w];
      acc.x += q.x; acc.y += q.y; acc.z += q.z; acc.w += q.w;
    }
    par ^= 1;
    return acc;
  };

  // Newton solve for the two per-component L1-projection thresholds.
  // getw(di,dj,wx,wy) yields the element of the vector being shrunk.
  // Roots match the Duchi sort formula exactly (piecewise-linear fixed point).
  auto newton2 = [&](auto getw, float rad, float wsx, float wsy,
                     float& oxv, float& oyv) {
    float s0 = 0.f, s1 = 0.f;
#pragma unroll
    for (int di = 0; di < TI; ++di)
#pragma unroll
      for (int dj = 0; dj < TJ; ++dj) {
        float wxv, wyv; getw(di, dj, wxv, wyv);
        s0 += fabsf(wxv); s1 += fabsf(wyv);
      }
    float4 tot = blk_red4(s0, s1, 0.f, 0.f);
    const float S0 = tot.x, S1 = tot.y;
    const float invD = 1.f / 16384.f;
    float t0, t1; bool d0 = false, d1 = false;
    if (S0 <= rad) { t0 = 0.f; d0 = true; }
    else { t0 = (S0 - rad) * invD; if (wsx > t0) t0 = wsx; }  // warm start (>= lower bound)
    if (S1 <= rad) { t1 = 0.f; d1 = true; }
    else { t1 = (S1 - rad) * invD; if (wsy > t1) t1 = wsy; }
    float np0 = -1.f, np1 = -1.f;
    for (int it2 = 0; it2 < 40; ++it2) {
      if (d0 && d1) break;
      float sa0 = 0.f, c0 = 0.f, sa1 = 0.f, c1 = 0.f;
#pragma unroll
      for (int di = 0; di < TI; ++di)
#pragma unroll
        for (int dj = 0; dj < TJ; ++dj) {
          float wxv, wyv; getw(di, dj, wxv, wyv);
          float ax = fabsf(wxv), ay = fabsf(wyv);
          if (ax > t0) { sa0 += ax; c0 += 1.f; }
          if (ay > t1) { sa1 += ay; c1 += 1.f; }
        }
      float4 rd = blk_red4(sa0, c0, sa1, c1);
      if (!d0) {
        if (rd.y < 0.5f) { t0 = (S0 - rad) * invD; np0 = -1.f; } // warm start overshot max
        else {
          float tn = (rd.x - rad) / rd.y;
          if (rd.y == np0 || tn == t0) d0 = true;
          t0 = tn; np0 = rd.y;
        }
      }
      if (!d1) {
        if (rd.w < 0.5f) { t1 = (S1 - rad) * invD; np1 = -1.f; }
        else {
          float tn = (rd.z - rad) / rd.w;
          if (rd.w == np1 || tn == t1) d1 = true;
          t1 = tn; np1 = rd.w;
        }
      }
    }
    oxv = t0; oyv = t1;
  };

  // t = m - div(vx,vy).  Exact reference boundary handling.
  auto div_to_t = [&](float (&vx)[TI][TJ], float (&vy)[TI][TJ]) {
#pragma unroll
    for (int dj = 0; dj < TJ; ++dj) sTop[ty][tx][dj] = vx[TI - 1][dj];  // my bottom row
#pragma unroll
    for (int di = 0; di < TI; ++di) sLeft[ty][tx][di] = vy[di][TJ - 1]; // my right col
    __syncthreads();
#pragma unroll
    for (int di = 0; di < TI; ++di) {
      const int i = i0 + di;
#pragma unroll
      for (int dj = 0; dj < TJ; ++dj) {
        const int j = j0 + dj;
        float up = (di > 0) ? vx[di - 1][dj] : ((ty > 0) ? sTop[ty - 1][tx][dj] : 0.f);
        float dx = (i == 0) ? vx[0][dj] : ((i == NN - 1) ? -up : vx[di][dj] - up);
        float lf = (dj > 0) ? vy[di][dj - 1] : ((tx > 0) ? sLeft[ty][tx - 1][di] : 0.f);
        float dy = (j == 0) ? vy[di][0] : ((j == NN - 1) ? -lf : vy[di][dj] - lf);
        t[di][dj] = m[di][dj] - (dx + dy);
      }
    }
    __syncthreads();  // halo reads done; buffers reusable
  };

  // consume(di,dj,gx,gy) with (gx,gy) = grad(t) at the point.
  auto grad_t = [&](auto&& consume) {
#pragma unroll
    for (int dj = 0; dj < TJ; ++dj) sTop[ty][tx][dj] = t[0][dj];        // my top row
#pragma unroll
    for (int di = 0; di < TI; ++di) sLeft[ty][tx][di] = t[di][0];       // my left col
    __syncthreads();
#pragma unroll
    for (int di = 0; di < TI; ++di) {
      const int i = i0 + di;
#pragma unroll
      for (int dj = 0; dj < TJ; ++dj) {
        const int j = j0 + dj;
        float dn = (di < TI - 1) ? t[di + 1][dj] : ((ty < GI - 1) ? sTop[ty + 1][tx][dj] : 0.f);
        float gx = (i == NN - 1) ? 0.f : dn - t[di][dj];
        float rt = (dj < TJ - 1) ? t[di][dj + 1] : ((tx < GJ - 1) ? sLeft[ty][tx + 1][di] : 0.f);
        float gy = (j == NN - 1) ? 0.f : rt - t[di][dj];
        consume(di, dj, gx, gy);
      }
    }
    __syncthreads();
  };

  float A = 0.f;
  float w1x = -1.f, w1y = -1.f, w3x = -1.f, w3y = -1.f;  // warm starts
  float thx, thy;

  for (int it = 0; it < NIT; ++it) {
    const float a_ = 0.5f * (MUc + sqrtf(MUc * MUc + 4.f * MUc * A));

    // ---- P1: v = shrink(u - xi, r*A);  y = (A u + a v)/(A+a)  -> into u regs
    if (it == 0) { thx = INFINITY; thy = INFINITY; }  // A==0 => radius 0 => identity
    else {
      newton2([&](int di, int dj, float& wxv, float& wyv) {
                wxv = ux[di][dj] - xx[di][dj];
                wyv = uy[di][dj] - xy[di][dj];
              }, r * A, w1x, w1y, thx, thy);
      w1x = thx; w1y = thy;
    }
    {
      const float inv = 1.f / (A + a_);
#pragma unroll
      for (int di = 0; di < TI; ++di)
#pragma unroll
        for (int dj = 0; dj < TJ; ++dj) {
          float vx = fminf(fmaxf(ux[di][dj] - xx[di][dj], -thx), thx);
          float vy = fminf(fmaxf(uy[di][dj] - xy[di][dj], -thy), thy);
          ux[di][dj] = (A * ux[di][dj] + a_ * vx) * inv;
          uy[di][dj] = (A * uy[di][dj] + a_ * vy) * inv;
        }
    }

    // ---- P2: t = M - div(y);  u_pre = y - (mu/2) grad(t)
    div_to_t(ux, uy);
    grad_t([&](int di, int dj, float gx, float gy) {
      ux[di][dj] -= 0.125f * gx;   // mu/2 = 0.125
      uy[di][dj] -= 0.125f * gy;
    });

    // ---- P3: u = shrink(u_pre, r*mu/2)
    newton2([&](int di, int dj, float& wxv, float& wyv) {
              wxv = ux[di][dj]; wyv = uy[di][dj];
            }, r * (MUc * 0.5f), w3x, w3y, thx, thy);
    w3x = thx; w3y = thy;
#pragma unroll
    for (int di = 0; di < TI; ++di)
#pragma unroll
      for (int dj = 0; dj < TJ; ++dj) {
        ux[di][dj] = fminf(fmaxf(ux[di][dj], -thx), thx);
        uy[di][dj] = fminf(fmaxf(uy[di][dj], -thy), thy);
      }

    // ---- P4: Mnew = M - div(u);  xi += a * grad(Mnew)
    div_to_t(ux, uy);   // t = Mnew
    grad_t([&](int di, int dj, float gx, float gy) {
      xx[di][dj] += a_ * gx;
      xy[di][dj] += a_ * gy;
    });

    A += a_;
  }

  // outputs: M1 = last Mnew (in t), u (interleaved last-dim 2)
  float* outM = out + (size_t)b * NN * NN;
  float* outU = out + (size_t)Nb * NN * NN + (size_t)b * NN * NN * 2;
#pragma unroll
  for (int di = 0; di < TI; ++di)
#pragma unroll
    for (int dj = 0; dj < TJ; ++dj) {
      const int idx = (i0 + di) * NN + (j0 + dj);
      outM[idx] = t[di][dj];
      outU[idx * 2]     = ux[di][dj];
      outU[idx * 2 + 1] = uy[di][dj];
    }
}

extern "C" void kernel_launch(void* const* d_in, const int* in_sizes, int n_in,
                              void* d_out, int out_size, void* d_ws, size_t ws_size,
                              hipStream_t stream) {
  const float* M  = (const float*)d_in[0];
  const float* tv = (const float*)d_in[1];
  const int Nb = in_sizes[0] / (NN * NN);   // 8
  tv_kernel<<<dim3(Nb), dim3(NTHREADS), 0, stream>>>(M, tv, (float*)d_out, Nb);
}

// Round 2
// 4825.494 us; speedup vs baseline: 1.1304x; 1.1304x over previous
//
#include <hip/hip_runtime.h>
#include <math.h>

#define NIT 200
#define NN 128
#define TI 4
#define TJ 8
#define GI 32   // NN/TI
#define GJ 16   // NN/TJ
#define NTHREADS 512
#define NWAVES 8

__global__ __launch_bounds__(NTHREADS, 1)
void tv_kernel(const float* __restrict__ Min, const float* __restrict__ tvr,
               float* __restrict__ out, int Nb)
{
  const float MUc = 0.25f;
  const int b   = blockIdx.x;
  const int tid = threadIdx.x;
  const int tx  = tid & (GJ - 1);   // 0..15
  const int ty  = tid >> 4;         // 0..31
  const int lane = tid & 63;
  const int wv   = tid >> 6;
  const int i0 = ty * TI;
  const int j0 = tx * TJ;

  // Conflict-free halo buffers: addr/4 = comp*512 + ty*16 + tx -> bank = lane%32 (2-way, free).
  // Index 0 = div-pass halos (u/y bottom rows & right cols), index 1 = grad-pass halos (t top rows & left cols).
  __shared__ float sTopW [2][TJ][GI][GJ];
  __shared__ float sLeftW[2][TI][GI][GJ];
  __shared__ float4 sRed[2][NWAVES];    // parity-buffered reduction scratch

  const float r = tvr[0];

  float m[TI][TJ], ux[TI][TJ], uy[TI][TJ], xx[TI][TJ], xy[TI][TJ], t[TI][TJ];
  float axc[TI][TJ], ayc[TI][TJ];   // cached |u - xi| for P1 Newton rounds

  const float* Mb = Min + (size_t)b * NN * NN;
#pragma unroll
  for (int di = 0; di < TI; ++di)
#pragma unroll
    for (int dj = 0; dj < TJ; ++dj) {
      m[di][dj] = Mb[(i0 + di) * NN + (j0 + dj)];
      ux[di][dj] = 0.f; uy[di][dj] = 0.f;
      xx[di][dj] = 0.f; xy[di][dj] = 0.f;
      t[di][dj] = 0.f; axc[di][dj] = 0.f; ayc[di][dj] = 0.f;
    }

  int par = 0;
  auto blk_red4 = [&](float v0, float v1, float v2, float v3) {
#pragma unroll
    for (int off = 32; off >= 1; off >>= 1) {
      v0 += __shfl_xor(v0, off, 64);
      v1 += __shfl_xor(v1, off, 64);
      v2 += __shfl_xor(v2, off, 64);
      v3 += __shfl_xor(v3, off, 64);
    }
    if (lane == 0) sRed[par][wv] = make_float4(v0, v1, v2, v3);
    __syncthreads();
    float4 acc = make_float4(0.f, 0.f, 0.f, 0.f);
#pragma unroll
    for (int w = 0; w < NWAVES; ++w) {
      float4 q = sRed[par][w];
      acc.x += q.x; acc.y += q.y; acc.z += q.z; acc.w += q.w;
    }
    par ^= 1;
    return acc;
  };
  auto blk_red2 = [&](float v0, float v1) {
#pragma unroll
    for (int off = 32; off >= 1; off >>= 1) {
      v0 += __shfl_xor(v0, off, 64);
      v1 += __shfl_xor(v1, off, 64);
    }
    if (lane == 0) sRed[par][wv] = make_float4(v0, v1, 0.f, 0.f);
    __syncthreads();
    float a0 = 0.f, a1 = 0.f;
#pragma unroll
    for (int w = 0; w < NWAVES; ++w) {
      float4 q = sRed[par][w];
      a0 += q.x; a1 += q.y;
    }
    par ^= 1;
    return make_float2(a0, a1);
  };

  // Newton rounds for the two per-component thresholds. S0/S1 are precomputed |.|_1 sums.
  // getabs(di,dj,a0,a1) yields per-element magnitudes. Converges to the exact Duchi root.
  auto newton_rounds = [&](auto getabs, float S0, float S1, float rad,
                           float& wsx, float& wsy, float& oxv, float& oyv) {
    const float invD = 1.f / 16384.f;
    float t0, t1; bool d0 = false, d1 = false;
    if (S0 <= rad) { t0 = 0.f; d0 = true; }
    else { t0 = (S0 - rad) * invD; t0 = fmaxf(t0, wsx); }   // warm start >= lower bound
    if (S1 <= rad) { t1 = 0.f; d1 = true; }
    else { t1 = (S1 - rad) * invD; t1 = fmaxf(t1, wsy); }
    float np0 = -1.f, np1 = -1.f;
    for (int k = 0; k < 40 && !(d0 && d1); ++k) {
      float sa0 = 0.f, c0 = 0.f, sa1 = 0.f, c1 = 0.f;
#pragma unroll
      for (int di = 0; di < TI; ++di)
#pragma unroll
        for (int dj = 0; dj < TJ; ++dj) {
          float a0v, a1v; getabs(di, dj, a0v, a1v);
          if (a0v > t0) { sa0 += a0v; c0 += 1.f; }
          if (a1v > t1) { sa1 += a1v; c1 += 1.f; }
        }
      float4 rd = blk_red4(sa0, c0, sa1, c1);
      if (!d0) {
        if (rd.y < 0.5f) { t0 = (S0 - rad) * invD; np0 = -1.f; }   // warm start above max
        else {
          float tn = __fdividef(rd.x - rad, rd.y);
          if (rd.y == np0 || tn == t0) d0 = true;
          t0 = tn; np0 = rd.y;
        }
      }
      if (!d1) {
        if (rd.w < 0.5f) { t1 = (S1 - rad) * invD; np1 = -1.f; }
        else {
          float tn = __fdividef(rd.z - rad, rd.w);
          if (rd.w == np1 || tn == t1) d1 = true;
          t1 = tn; np1 = rd.w;
        }
      }
    }
    oxv = t0; oyv = t1; wsx = t0; wsy = t1;
  };

  // div pass: t = m - div(ux,uy); reads buf0 halos (written earlier), writes t-halos to buf1.
  auto div_pass = [&]() {
#pragma unroll
    for (int di = 0; di < TI; ++di) {
      const int i = i0 + di;
#pragma unroll
      for (int dj = 0; dj < TJ; ++dj) {
        const int j = j0 + dj;
        float up, lf;
        if (di > 0) up = ux[di - 1][dj];
        else { float h = sTopW[0][dj][(ty > 0) ? ty - 1 : 0][tx]; up = (ty > 0) ? h : 0.f; }
        if (dj > 0) lf = uy[di][dj - 1];
        else { float h = sLeftW[0][di][ty][(tx > 0) ? tx - 1 : 0]; lf = (tx > 0) ? h : 0.f; }
        float vxv = (i == NN - 1) ? 0.f : ux[di][dj];
        float vyv = (j == NN - 1) ? 0.f : uy[di][dj];
        float tt = m[di][dj] - ((vxv - up) + (vyv - lf));
        t[di][dj] = tt;
        if (di == 0) sTopW[1][dj][ty][tx] = tt;    // my top row -> grad halo
        if (dj == 0) sLeftW[1][di][ty][tx] = tt;   // my left col -> grad halo
      }
    }
  };

  // grad pass: reads buf1 halos; consume(di,dj,gx,gy) with (gx,gy)=grad(t).
  auto grad_pass = [&](auto&& consume) {
#pragma unroll
    for (int di = 0; di < TI; ++di) {
      const int i = i0 + di;
#pragma unroll
      for (int dj = 0; dj < TJ; ++dj) {
        const int j = j0 + dj;
        float dn, rt;
        if (di < TI - 1) dn = t[di + 1][dj];
        else dn = sTopW[1][dj][(ty < GI - 1) ? ty + 1 : ty][tx];
        if (dj < TJ - 1) rt = t[di][dj + 1];
        else rt = sLeftW[1][di][ty][(tx < GJ - 1) ? tx + 1 : tx];
        float gx = (i == NN - 1) ? 0.f : dn - t[di][dj];
        float gy = (j == NN - 1) ? 0.f : rt - t[di][dj];
        consume(di, dj, gx, gy);
      }
    }
  };

  float A = 0.f;
  float w1x = -1.f, w1y = -1.f, w3x = -1.f, w3y = -1.f;
  float S0p = 0.f, S1p = 0.f;   // fused P1 sums (|u - xi|), produced at end of prev iter
  float thx, thy;

  for (int it = 0; it < NIT; ++it) {
    const float a_ = 0.5f * (MUc + sqrtf(MUc * MUc + 4.f * MUc * A));

    // ---- P1 thresholds (A==0 at it==0 -> radius 0 -> identity)
    if (it == 0) { thx = INFINITY; thy = INFINITY; }
    else newton_rounds([&](int di, int dj, float& a0v, float& a1v) {
                         a0v = axc[di][dj]; a1v = ayc[di][dj];
                       }, S0p, S1p, r * A, w1x, w1y, thx, thy);

    // ---- P2a: y = (A u + a v)/(A+a) with v = clamp(u - xi, ±th); write y halos (buf0)
    {
      const float inv = 1.f / (A + a_);
#pragma unroll
      for (int di = 0; di < TI; ++di)
#pragma unroll
        for (int dj = 0; dj < TJ; ++dj) {
          float wxv = ux[di][dj] - xx[di][dj];
          float wyv = uy[di][dj] - xy[di][dj];
          float vx = fminf(fmaxf(wxv, -thx), thx);
          float vy = fminf(fmaxf(wyv, -thy), thy);
          ux[di][dj] = (A * ux[di][dj] + a_ * vx) * inv;
          uy[di][dj] = (A * uy[di][dj] + a_ * vy) * inv;
        }
#pragma unroll
      for (int dj = 0; dj < TJ; ++dj) sTopW[0][dj][ty][tx] = ux[TI - 1][dj];
#pragma unroll
      for (int di = 0; di < TI; ++di) sLeftW[0][di][ty][tx] = uy[di][TJ - 1];
    }
    __syncthreads();
    div_pass();            // t = M - div(y); t-halos -> buf1

    // ---- P2b: u_pre = y - (mu/2) grad(t); fused P3 L1-sums
    __syncthreads();
    {
      float s0 = 0.f, s1 = 0.f;
      grad_pass([&](int di, int dj, float gx, float gy) {
        ux[di][dj] -= 0.125f * gx;
        uy[di][dj] -= 0.125f * gy;
        s0 += fabsf(ux[di][dj]);
        s1 += fabsf(uy[di][dj]);
      });
      float2 S3 = blk_red2(s0, s1);

      // ---- P3: u = clamp(u_pre, ±th3)
      newton_rounds([&](int di, int dj, float& a0v, float& a1v) {
                      a0v = fabsf(ux[di][dj]); a1v = fabsf(uy[di][dj]);
                    }, S3.x, S3.y, r * (MUc * 0.5f), w3x, w3y, thx, thy);
    }
    // ---- P4a: apply clamp; write u halos (buf0)
#pragma unroll
    for (int di = 0; di < TI; ++di)
#pragma unroll
      for (int dj = 0; dj < TJ; ++dj) {
        ux[di][dj] = fminf(fmaxf(ux[di][dj], -thx), thx);
        uy[di][dj] = fminf(fmaxf(uy[di][dj], -thy), thy);
      }
#pragma unroll
    for (int dj = 0; dj < TJ; ++dj) sTopW[0][dj][ty][tx] = ux[TI - 1][dj];
#pragma unroll
    for (int di = 0; di < TI; ++di) sLeftW[0][di][ty][tx] = uy[di][TJ - 1];
    __syncthreads();
    div_pass();            // t = Mnew; t-halos -> buf1

    // ---- P4b: xi += a grad(Mnew); fused next-P1 w = u - xi, cache |w|, L1-sums
    __syncthreads();
    {
      float s0 = 0.f, s1 = 0.f;
      grad_pass([&](int di, int dj, float gx, float gy) {
        xx[di][dj] += a_ * gx;
        xy[di][dj] += a_ * gy;
        float wxv = ux[di][dj] - xx[di][dj];
        float wyv = uy[di][dj] - xy[di][dj];
        axc[di][dj] = fabsf(wxv);
        ayc[di][dj] = fabsf(wyv);
        s0 += axc[di][dj];
        s1 += ayc[di][dj];
      });
      float2 SP = blk_red2(s0, s1);
      S0p = SP.x; S1p = SP.y;
    }
    A += a_;
  }

  // outputs: M1 = last Mnew (in t), u (interleaved last-dim 2)
  float* outM = out + (size_t)b * NN * NN;
  float* outU = out + (size_t)Nb * NN * NN + (size_t)b * NN * NN * 2;
#pragma unroll
  for (int di = 0; di < TI; ++di)
#pragma unroll
    for (int dj = 0; dj < TJ; ++dj) {
      const int idx = (i0 + di) * NN + (j0 + dj);
      outM[idx] = t[di][dj];
      outU[idx * 2]     = ux[di][dj];
      outU[idx * 2 + 1] = uy[di][dj];
    }
}

extern "C" void kernel_launch(void* const* d_in, const int* in_sizes, int n_in,
                              void* d_out, int out_size, void* d_ws, size_t ws_size,
                              hipStream_t stream) {
  const float* M  = (const float*)d_in[0];
  const float* tv = (const float*)d_in[1];
  const int Nb = in_sizes[0] / (NN * NN);   // 8
  tv_kernel<<<dim3(Nb), dim3(NTHREADS), 0, stream>>>(M, tv, (float*)d_out, Nb);
}